// Round 3
// baseline (719.354 us; speedup 1.0000x reference)
//
#include <hip/hip_runtime.h>
#include <stdint.h>

// ---------- types ----------
typedef __bf16    bf16x8 __attribute__((ext_vector_type(8)));
typedef float     f32x4  __attribute__((ext_vector_type(4)));
typedef _Float16  f16;
typedef _Float16  f16x4  __attribute__((ext_vector_type(4)));

#define DEV __device__ __forceinline__

DEV ushort f2bf(float f) {               // RTNE float -> bf16 bits
  union { float f; uint32_t u; } v; v.f = f;
  uint32_t u = v.u;
  return (ushort)((u + 0x7fffu + ((u >> 16) & 1u)) >> 16);
}

// async global->LDS, 16B per lane. LDS dest must be wave-uniform base + lane*16.
DEV void async16(const void* g, void* l) {
  __builtin_amdgcn_global_load_lds(
      (__attribute__((address_space(1))) void*)(uintptr_t)g,
      (__attribute__((address_space(3))) void*)(uint32_t)(uintptr_t)l,
      16, 0, 0);
}

// ---------- kernel 1: mod = t @ mod_w.T  (16 x 2048, K=1024, fp32) ----------
__global__ __launch_bounds__(64)
void mod_gemm_kernel(const float* __restrict__ t, const float* __restrict__ w,
                     float* __restrict__ mod) {
  int j = blockIdx.x;
  int lane = threadIdx.x;
  float wr[16];
#pragma unroll
  for (int i = 0; i < 16; ++i) wr[i] = w[(size_t)j * 1024 + lane + i * 64];
  for (int b = 0; b < 16; ++b) {
    float s = 0.f;
#pragma unroll
    for (int i = 0; i < 16; ++i) s += wr[i] * t[b * 1024 + lane + i * 64];
#pragma unroll
    for (int m = 32; m >= 1; m >>= 1) s += __shfl_xor(s, m, 64);
    if (lane == 0) mod[b * 2048 + j] = s;
  }
}

// ---------- kernel 2: RMSNorm + modulate -> bf16 h ----------
__global__ __launch_bounds__(256)
void rms_mod_kernel(const float* __restrict__ x, const float* __restrict__ nw,
                    const float* __restrict__ mod, ushort* __restrict__ h) {
  int row = blockIdx.x;
  int b = row >> 10;
  int tid = threadIdx.x;
  const float4 xv = *(const float4*)(x + (size_t)row * 1024 + tid * 4);
  float ss = xv.x * xv.x + xv.y * xv.y + xv.z * xv.z + xv.w * xv.w;
#pragma unroll
  for (int m = 32; m >= 1; m >>= 1) ss += __shfl_xor(ss, m, 64);
  __shared__ float red[4];
  int w = tid >> 6, lane = tid & 63;
  if (lane == 0) red[w] = ss;
  __syncthreads();
  float tot = red[0] + red[1] + red[2] + red[3];
  float rn = rsqrtf(tot * (1.f / 1024.f) + 1e-6f);
  float4 wv = *(const float4*)(nw + tid * 4);
  float4 sc = *(const float4*)(mod + (size_t)b * 2048 + tid * 4);
  float4 sh = *(const float4*)(mod + (size_t)b * 2048 + 1024 + tid * 4);
  ushort4 o;
  o.x = f2bf(xv.x * rn * wv.x * (1.f + sc.x) + sh.x);
  o.y = f2bf(xv.y * rn * wv.y * (1.f + sc.y) + sh.y);
  o.z = f2bf(xv.z * rn * wv.z * (1.f + sc.z) + sh.z);
  o.w = f2bf(xv.w * rn * wv.w * (1.f + sc.w) + sh.w);
  *(ushort4*)(h + (size_t)row * 1024 + tid * 4) = o;
}

// ---------- kernel 3: fp32 -> bf16 cast ----------
__global__ __launch_bounds__(256)
void cvt_bf16_kernel(const float* __restrict__ in, ushort* __restrict__ out, int n4) {
  int i = blockIdx.x * 256 + threadIdx.x;
  if (i < n4) {
    float4 v = ((const float4*)in)[i];
    ushort4 o;
    o.x = f2bf(v.x); o.y = f2bf(v.y); o.z = f2bf(v.z); o.w = f2bf(v.w);
    ((ushort4*)out)[i] = o;
  }
}

// ---------- kernel 3b: split qkv_w (3072x1024 fp32) -> wqk (2048 rows) + wv (1024 rows), bf16
__global__ __launch_bounds__(256)
void cvt_split_kernel(const float* __restrict__ qkvw, ushort* __restrict__ wqk,
                      ushort* __restrict__ wv) {
  int j = blockIdx.x;                     // 0..3071
  int tid = threadIdx.x;
  uint32_t hd = (uint32_t)j / 192u;
  uint32_t rem = (uint32_t)j - hd * 192u;
  ushort* dst = (rem < 128u) ? (wqk + (size_t)(hd * 128u + rem) * 1024)
                             : (wv + (size_t)(hd * 64u + (rem - 128u)) * 1024);
  float4 v = ((const float4*)(qkvw + (size_t)j * 1024))[tid];
  ushort4 o;
  o.x = f2bf(v.x); o.y = f2bf(v.y); o.z = f2bf(v.z); o.w = f2bf(v.w);
  ((ushort4*)dst)[tid] = o;
}

// ---------- GEMM: C[M][N] = A[M][K] * B[N][K]^T, bf16 in, 128x128 tile ----------
// MODE 0: fp32 out, row stride 1024 (WO proj)
// MODE 1: scatter f16 to qb/kb; cols are [head(16)][part(2)][d(64)] (N=2048)
// MODE 2: V^T: A=Wv rows = v-features f, cols = tokens; store f16 row-major (N=16384)
template <int MODE>
__global__ __launch_bounds__(256, 3)
void gemm_bt_kernel(const ushort* __restrict__ A, const ushort* __restrict__ B,
                    float* __restrict__ outf,
                    f16* __restrict__ qb, f16* __restrict__ kb,
                    f16* __restrict__ vtb) {
  __shared__ ushort As[512 * 8];
  __shared__ ushort Bs[512 * 8];
  const int K = 1024;
  const int m0 = blockIdx.y * 128, n0 = blockIdx.x * 128;
  const int tid = threadIdx.x;
  const int w = tid >> 6, lane = tid & 63, quad = lane >> 4, l15 = lane & 15;
  const int wm = (w >> 1) * 64, wn = (w & 1) * 64;
  const f32x4 fzero = {0.f, 0.f, 0.f, 0.f};
  f32x4 acc[4][4];
#pragma unroll
  for (int a = 0; a < 4; ++a)
#pragma unroll
    for (int b = 0; b < 4; ++b) acc[a][b] = fzero;

  const int s0 = tid, s1 = 256 + tid;
  const int r0 = s0 >> 2, c0 = (s0 & 3) ^ ((r0 >> 1) & 3);
  const int r1 = s1 >> 2, c1 = (s1 & 3) ^ ((r1 >> 1) & 3);
  const ushort* Ag0 = A + (size_t)(m0 + r0) * K + c0 * 8;
  const ushort* Ag1 = A + (size_t)(m0 + r1) * K + c1 * 8;
  const ushort* Bg0 = B + (size_t)(n0 + r0) * K + c0 * 8;
  const ushort* Bg1 = B + (size_t)(n0 + r1) * K + c1 * 8;

  for (int kt = 0; kt < K; kt += 32) {
    async16(Ag0 + kt, As + s0 * 8);
    async16(Ag1 + kt, As + s1 * 8);
    async16(Bg0 + kt, Bs + s0 * 8);
    async16(Bg1 + kt, Bs + s1 * 8);
    __syncthreads();
    bf16x8 af[4], bfr[4];
#pragma unroll
    for (int tm = 0; tm < 4; ++tm) {
      int r = wm + tm * 16 + l15;
      int cs = quad ^ ((r >> 1) & 3);
      af[tm] = *(const bf16x8*)(As + (r * 4 + cs) * 8);
    }
#pragma unroll
    for (int tn = 0; tn < 4; ++tn) {
      int r = wn + tn * 16 + l15;
      int cs = quad ^ ((r >> 1) & 3);
      bfr[tn] = *(const bf16x8*)(Bs + (r * 4 + cs) * 8);
    }
#pragma unroll
    for (int tm = 0; tm < 4; ++tm)
#pragma unroll
      for (int tn = 0; tn < 4; ++tn)
        acc[tm][tn] = __builtin_amdgcn_mfma_f32_16x16x32_bf16(af[tm], bfr[tn],
                                                              acc[tm][tn], 0, 0, 0);
    __syncthreads();
  }

  if (MODE == 0) {
#pragma unroll
    for (int tm = 0; tm < 4; ++tm)
#pragma unroll
      for (int tn = 0; tn < 4; ++tn) {
        int col = n0 + wn + tn * 16 + l15;
#pragma unroll
        for (int r = 0; r < 4; ++r) {
          int row = m0 + wm + tm * 16 + quad * 4 + r;
          outf[(size_t)row * 1024 + col] = acc[tm][tn][r];
        }
      }
  } else if (MODE == 1) {
    // col in [0,2048): head=col>>7, part=(col>>6)&1, d=col&63
#pragma unroll
    for (int tm = 0; tm < 4; ++tm)
#pragma unroll
      for (int tn = 0; tn < 4; ++tn) {
        int col = n0 + wn + tn * 16 + l15;
        int hd = col >> 7, part = (col >> 6) & 1, d = col & 63;
#pragma unroll
        for (int r = 0; r < 4; ++r) {
          int row = m0 + wm + tm * 16 + quad * 4 + r;
          int b = row >> 10, n = row & 1023;
          size_t bh = (size_t)b * 16 + hd;
          f16 v = (f16)acc[tm][tn][r];
          if (part == 0) qb[(bh * 1024 + n) * 64 + d] = v;
          else           kb[(bh * 1024 + n) * 64 + d] = v;
        }
      }
  } else {
    // V^T: row m = v-feature f (= hd*64+d), col = token (b*1024+nn)
    // vtb layout [b][f][nn] == [bh][d][n]; 16-lane stores are 32B contiguous
#pragma unroll
    for (int tm = 0; tm < 4; ++tm)
#pragma unroll
      for (int tn = 0; tn < 4; ++tn) {
        int col = n0 + wn + tn * 16 + l15;
        int b = col >> 10, nn = col & 1023;
#pragma unroll
        for (int r = 0; r < 4; ++r) {
          int f = m0 + wm + tm * 16 + quad * 4 + r;
          vtb[((size_t)(b * 1024 + f)) * 1024 + nn] = (f16)acc[tm][tn][r];
        }
      }
  }
}

// ---------- kernel 5: 2D RoPE in-place (f16); q gets 0.125*log2(e) fold ----------
__global__ __launch_bounds__(256)
void rope_kernel(f16* __restrict__ qb, f16* __restrict__ kb) {
  size_t idx = (size_t)blockIdx.x * 256 + threadIdx.x;
  int p = (int)(idx & 31);
  size_t rowi = idx >> 5;
  int n = (int)(rowi & 1023);
  int j = p & 15;
  float pos = (p < 16) ? (float)(n & 31) : (float)(n >> 5);
  float theta = __powf(10000.f, -(float)j * (1.f / 16.f));
  float ang = pos * theta;
  float sn, cs;
  __sincosf(ang, &sn, &cs);
  const float QS = 0.125f * 1.44269504f;   // attn scale * log2(e), folded into q
  size_t a = rowi * 64 + (size_t)p * 2;
  union U { uint32_t u; f16 h[2]; };
  U qu; qu.u = *(const uint32_t*)(qb + a);
  float x0 = (float)qu.h[0], x1 = (float)qu.h[1];
  U qo;
  qo.h[0] = (f16)((x0 * cs - x1 * sn) * QS);
  qo.h[1] = (f16)((x1 * cs + x0 * sn) * QS);
  *(uint32_t*)(qb + a) = qo.u;
  U ku; ku.u = *(const uint32_t*)(kb + a);
  float k0 = (float)ku.h[0], k1 = (float)ku.h[1];
  U ko;
  ko.h[0] = (f16)(k0 * cs - k1 * sn);
  ko.h[1] = (f16)(k1 * cs + k0 * sn);
  *(uint32_t*)(kb + a) = ko.u;
}

// ---------- kernel 6: flash attention, in-register P (S^T trick), f16 MFMA ----------
// grid = (bh=256, qb=8): all q-blocks of one bh land on XCD bh%8 -> K/V L2 reuse.
__global__ __launch_bounds__(256, 4)
void attn_kernel(const f16* __restrict__ qbuf, const f16* __restrict__ kbuf,
                 const f16* __restrict__ vtbuf, ushort* __restrict__ aout) {
  __shared__ f16 Ks[128 * 64];   // [krow][64d], 16B col c swizzled: c^(row&7)
  __shared__ f16 Vs[64 * 128];   // V^T [d][128k], 16B col c swizzled: c^(row&15)

  const int bh = blockIdx.x;
  const int q0 = blockIdx.y * 128;
  const f16* Qg = qbuf + (size_t)bh * 1024 * 64;
  const f16* Kg = kbuf + (size_t)bh * 1024 * 64;
  const f16* Vg = vtbuf + (size_t)bh * 64 * 1024;
  const int tid = threadIdx.x;
  const int w = tid >> 6, lane = tid & 63, quad = lane >> 4, l15 = lane & 15;
  const f32x4 fzero = {0.f, 0.f, 0.f, 0.f};

  // Q B-fragments straight from global: B[n=q=l15][k=d=quad*4+i]
  f16x4 qf[2][4];
#pragma unroll
  for (int qs = 0; qs < 2; ++qs)
#pragma unroll
    for (int dc = 0; dc < 4; ++dc)
      qf[qs][dc] = *(const f16x4*)(Qg + (size_t)(q0 + w * 32 + qs * 16 + l15) * 64 +
                                   dc * 16 + quad * 4);

  f32x4 oacc[2][4];
#pragma unroll
  for (int qs = 0; qs < 2; ++qs)
#pragma unroll
    for (int ds = 0; ds < 4; ++ds) oacc[qs][ds] = fzero;
  float mrun[2] = {-1e30f, -1e30f}, lrun[2] = {0.f, 0.f};

  for (int kt = 0; kt < 1024; kt += 128) {
#pragma unroll
    for (int i = 0; i < 4; ++i) {       // K tile
      int u = i * 256 + tid, r = u >> 3, c = u & 7;
      async16(Kg + (size_t)(kt + r) * 64 + (c ^ (r & 7)) * 8, Ks + u * 8);
    }
#pragma unroll
    for (int i = 0; i < 4; ++i) {       // V^T tile
      int u = i * 256 + tid, r = u >> 4, c = u & 15;
      async16(Vg + (size_t)r * 1024 + kt + (c ^ (r & 15)) * 8, Vs + u * 8);
    }
    __syncthreads();

    // S^T: D[k=quad*4+r][q=l15], chained over d
    f32x4 sacc[2][8];
#pragma unroll
    for (int qs = 0; qs < 2; ++qs)
#pragma unroll
      for (int ks = 0; ks < 8; ++ks) sacc[qs][ks] = fzero;
#pragma unroll
    for (int ks = 0; ks < 8; ++ks) {
#pragma unroll
      for (int dc = 0; dc < 4; ++dc) {
        int row = ks * 16 + l15;
        int c16 = dc * 2 + (quad >> 1);
        f16x4 kf = *(const f16x4*)(Ks + row * 64 + ((c16 ^ (row & 7)) * 8) + (quad & 1) * 4);
        sacc[0][ks] = __builtin_amdgcn_mfma_f32_16x16x16f16(kf, qf[0][dc], sacc[0][ks], 0, 0, 0);
        sacc[1][ks] = __builtin_amdgcn_mfma_f32_16x16x16f16(kf, qf[1][dc], sacc[1][ks], 0, 0, 0);
      }
    }

    // online softmax fully in registers (lane owns q=l15; cross-quad shfl only)
    f16x4 pf[2][8];
#pragma unroll
    for (int qs = 0; qs < 2; ++qs) {
      float mx = -1e30f;
#pragma unroll
      for (int ks = 0; ks < 8; ++ks)
#pragma unroll
        for (int i = 0; i < 4; ++i) mx = fmaxf(mx, sacc[qs][ks][i]);
      mx = fmaxf(mx, __shfl_xor(mx, 16, 64));
      mx = fmaxf(mx, __shfl_xor(mx, 32, 64));
      float mnew = fmaxf(mrun[qs], mx);
      float alpha = exp2f(mrun[qs] - mnew);
      mrun[qs] = mnew;
      float rs = 0.f;
#pragma unroll
      for (int ks = 0; ks < 8; ++ks)
#pragma unroll
        for (int i = 0; i < 4; ++i) {
          float p = exp2f(sacc[qs][ks][i] - mnew);
          rs += p;
          pf[qs][ks][i] = (f16)p;
        }
      rs += __shfl_xor(rs, 16, 64);
      rs += __shfl_xor(rs, 32, 64);
      lrun[qs] = lrun[qs] * alpha + rs;
      float ar[4];
#pragma unroll
      for (int r = 0; r < 4; ++r) ar[r] = __shfl(alpha, quad * 4 + r, 64);
#pragma unroll
      for (int ds = 0; ds < 4; ++ds)
#pragma unroll
        for (int r = 0; r < 4; ++r) oacc[qs][ds][r] *= ar[r];
    }

    // O += P V : P already in A layout; V^T B-frag from LDS
#pragma unroll
    for (int ks = 0; ks < 8; ++ks) {
#pragma unroll
      for (int ds = 0; ds < 4; ++ds) {
        int row = ds * 16 + l15;
        int c16 = ks * 2 + (quad >> 1);
        f16x4 vf = *(const f16x4*)(Vs + row * 128 + ((c16 ^ (row & 15)) * 8) + (quad & 1) * 4);
        oacc[0][ds] = __builtin_amdgcn_mfma_f32_16x16x16f16(pf[0][ks], vf, oacc[0][ds], 0, 0, 0);
        oacc[1][ds] = __builtin_amdgcn_mfma_f32_16x16x16f16(pf[1][ks], vf, oacc[1][ds], 0, 0, 0);
      }
    }
    __syncthreads();
  }

  // epilogue: O /= l, write [b][n][h*64+d] bf16
  const int b = bh >> 4, hh = bh & 15;
#pragma unroll
  for (int qs = 0; qs < 2; ++qs) {
    float linv[4];
#pragma unroll
    for (int r = 0; r < 4; ++r) linv[r] = 1.f / __shfl(lrun[qs], quad * 4 + r, 64);
#pragma unroll
    for (int ds = 0; ds < 4; ++ds)
#pragma unroll
      for (int r = 0; r < 4; ++r) {
        int n = q0 + w * 32 + qs * 16 + quad * 4 + r;
        int d = ds * 16 + l15;
        aout[((size_t)b * 1024 + n) * 1024 + hh * 64 + d] = f2bf(oacc[qs][ds][r] * linv[r]);
      }
  }
}

// ---------- launch ----------
extern "C" void kernel_launch(void* const* d_in, const int* in_sizes, int n_in,
                              void* d_out, int out_size, void* d_ws, size_t ws_size,
                              hipStream_t stream) {
  const float* x    = (const float*)d_in[0];
  const float* t    = (const float*)d_in[1];
  const float* nw   = (const float*)d_in[2];
  const float* mw   = (const float*)d_in[3];
  const float* qkvw = (const float*)d_in[4];
  const float* wow  = (const float*)d_in[5];
  float* out = (float*)d_out;
  char* ws = (char*)d_ws;

  float*  modbuf  = (float*)(ws);                    // 131072 B
  ushort* hbuf    = (ushort*)(ws + 131072);          // 32 MB (bf16)
  ushort* wqk_b   = (ushort*)(ws + 33685504);        // 2048*1024*2 = 4 MB
  ushort* wv_b    = (ushort*)(ws + 37879808);        // 1024*1024*2 = 2 MB
  ushort* wow_b   = (ushort*)(ws + 39976960);        // 2 MB
  f16*    qbuf    = (f16*)(ws + 42074112);           // 32 MB
  f16*    kbuf    = (f16*)(ws + 75628544);           // 32 MB
  f16*    vtbuf   = (f16*)(ws + 109182976);          // 32 MB (V^T [b][f][n])
  ushort* abuf    = (ushort*)(ws + 142737408);       // 32 MB (bf16)

  mod_gemm_kernel<<<dim3(2048), dim3(64), 0, stream>>>(t, mw, modbuf);
  rms_mod_kernel<<<dim3(16384), dim3(256), 0, stream>>>(x, nw, modbuf, hbuf);
  cvt_split_kernel<<<dim3(3072), dim3(256), 0, stream>>>(qkvw, wqk_b, wv_b);
  cvt_bf16_kernel<<<dim3(1024), dim3(256), 0, stream>>>(wow, wow_b, 262144);
  // QK proj: C[16384][2048] = h @ wqk^T, scatter to qb/kb
  gemm_bt_kernel<1><<<dim3(16, 128), dim3(256), 0, stream>>>(
      hbuf, wqk_b, nullptr, qbuf, kbuf, nullptr);
  // V^T: C[1024][16384] = wv @ h^T, stored row-major = V^T
  gemm_bt_kernel<2><<<dim3(128, 8), dim3(256), 0, stream>>>(
      wv_b, hbuf, nullptr, nullptr, nullptr, vtbuf);
  rope_kernel<<<dim3(32768), dim3(256), 0, stream>>>(qbuf, kbuf);
  attn_kernel<<<dim3(256, 8), dim3(256), 0, stream>>>(qbuf, kbuf, vtbuf, abuf);
  gemm_bt_kernel<0><<<dim3(8, 128), dim3(256), 0, stream>>>(
      abuf, wow_b, out, nullptr, nullptr, nullptr);
}

// Round 4
// 538.428 us; speedup vs baseline: 1.3360x; 1.3360x over previous
//
#include <hip/hip_runtime.h>
#include <stdint.h>

// ---------- types ----------
typedef __bf16    bf16x8 __attribute__((ext_vector_type(8)));
typedef float     f32x4  __attribute__((ext_vector_type(4)));
typedef _Float16  f16;
typedef _Float16  f16x4  __attribute__((ext_vector_type(4)));

#define DEV __device__ __forceinline__

DEV ushort f2bf(float f) {               // RTNE float -> bf16 bits
  union { float f; uint32_t u; } v; v.f = f;
  uint32_t u = v.u;
  return (ushort)((u + 0x7fffu + ((u >> 16) & 1u)) >> 16);
}

// async global->LDS, 16B per lane. LDS dest must be wave-uniform base + lane*16.
DEV void async16(const void* g, void* l) {
  __builtin_amdgcn_global_load_lds(
      (__attribute__((address_space(1))) void*)(uintptr_t)g,
      (__attribute__((address_space(3))) void*)(uint32_t)(uintptr_t)l,
      16, 0, 0);
}

// ---------- kernel 1: mod = t @ mod_w.T  (16 x 2048, K=1024, fp32) ----------
__global__ __launch_bounds__(64)
void mod_gemm_kernel(const float* __restrict__ t, const float* __restrict__ w,
                     float* __restrict__ mod) {
  int j = blockIdx.x;
  int lane = threadIdx.x;
  float wr[16];
#pragma unroll
  for (int i = 0; i < 16; ++i) wr[i] = w[(size_t)j * 1024 + lane + i * 64];
  for (int b = 0; b < 16; ++b) {
    float s = 0.f;
#pragma unroll
    for (int i = 0; i < 16; ++i) s += wr[i] * t[b * 1024 + lane + i * 64];
#pragma unroll
    for (int m = 32; m >= 1; m >>= 1) s += __shfl_xor(s, m, 64);
    if (lane == 0) mod[b * 2048 + j] = s;
  }
}

// ---------- kernel 2: RMSNorm + modulate -> bf16 h ----------
__global__ __launch_bounds__(256)
void rms_mod_kernel(const float* __restrict__ x, const float* __restrict__ nw,
                    const float* __restrict__ mod, ushort* __restrict__ h) {
  int row = blockIdx.x;
  int b = row >> 10;
  int tid = threadIdx.x;
  const float4 xv = *(const float4*)(x + (size_t)row * 1024 + tid * 4);
  float ss = xv.x * xv.x + xv.y * xv.y + xv.z * xv.z + xv.w * xv.w;
#pragma unroll
  for (int m = 32; m >= 1; m >>= 1) ss += __shfl_xor(ss, m, 64);
  __shared__ float red[4];
  int w = tid >> 6, lane = tid & 63;
  if (lane == 0) red[w] = ss;
  __syncthreads();
  float tot = red[0] + red[1] + red[2] + red[3];
  float rn = rsqrtf(tot * (1.f / 1024.f) + 1e-6f);
  float4 wv = *(const float4*)(nw + tid * 4);
  float4 sc = *(const float4*)(mod + (size_t)b * 2048 + tid * 4);
  float4 sh = *(const float4*)(mod + (size_t)b * 2048 + 1024 + tid * 4);
  ushort4 o;
  o.x = f2bf(xv.x * rn * wv.x * (1.f + sc.x) + sh.x);
  o.y = f2bf(xv.y * rn * wv.y * (1.f + sc.y) + sh.y);
  o.z = f2bf(xv.z * rn * wv.z * (1.f + sc.z) + sh.z);
  o.w = f2bf(xv.w * rn * wv.w * (1.f + sc.w) + sh.w);
  *(ushort4*)(h + (size_t)row * 1024 + tid * 4) = o;
}

// ---------- kernel 3: fp32 -> bf16 cast ----------
__global__ __launch_bounds__(256)
void cvt_bf16_kernel(const float* __restrict__ in, ushort* __restrict__ out, int n4) {
  int i = blockIdx.x * 256 + threadIdx.x;
  if (i < n4) {
    float4 v = ((const float4*)in)[i];
    ushort4 o;
    o.x = f2bf(v.x); o.y = f2bf(v.y); o.z = f2bf(v.z); o.w = f2bf(v.w);
    ((ushort4*)out)[i] = o;
  }
}

// ---------- kernel 3b: split qkv_w (3072x1024 fp32) -> wqk (2048 rows) + wv (1024 rows), bf16
__global__ __launch_bounds__(256)
void cvt_split_kernel(const float* __restrict__ qkvw, ushort* __restrict__ wqk,
                      ushort* __restrict__ wv) {
  int j = blockIdx.x;                     // 0..3071
  int tid = threadIdx.x;
  uint32_t hd = (uint32_t)j / 192u;
  uint32_t rem = (uint32_t)j - hd * 192u;
  ushort* dst = (rem < 128u) ? (wqk + (size_t)(hd * 128u + rem) * 1024)
                             : (wv + (size_t)(hd * 64u + (rem - 128u)) * 1024);
  float4 v = ((const float4*)(qkvw + (size_t)j * 1024))[tid];
  ushort4 o;
  o.x = f2bf(v.x); o.y = f2bf(v.y); o.z = f2bf(v.z); o.w = f2bf(v.w);
  ((ushort4*)dst)[tid] = o;
}

// ---------- GEMM: C[M][N] = A[M][K] * B[N][K]^T, bf16 in, 128x128 tile ----------
// MODE 0: fp32 out, row stride 1024 (WO proj)
// MODE 1: scatter f16 to qb/kb; cols are [head(16)][part(2)][d(64)] (N=2048)
// MODE 2: V^T: A=Wv rows = v-features f, cols = tokens; store f16 row-major (N=16384)
template <int MODE>
__global__ __launch_bounds__(256, 3)
void gemm_bt_kernel(const ushort* __restrict__ A, const ushort* __restrict__ B,
                    float* __restrict__ outf,
                    f16* __restrict__ qb, f16* __restrict__ kb,
                    f16* __restrict__ vtb) {
  __shared__ ushort As[512 * 8];
  __shared__ ushort Bs[512 * 8];
  const int K = 1024;
  const int m0 = blockIdx.y * 128, n0 = blockIdx.x * 128;
  const int tid = threadIdx.x;
  const int w = tid >> 6, lane = tid & 63, quad = lane >> 4, l15 = lane & 15;
  const int wm = (w >> 1) * 64, wn = (w & 1) * 64;
  const f32x4 fzero = {0.f, 0.f, 0.f, 0.f};
  f32x4 acc[4][4];
#pragma unroll
  for (int a = 0; a < 4; ++a)
#pragma unroll
    for (int b = 0; b < 4; ++b) acc[a][b] = fzero;

  const int s0 = tid, s1 = 256 + tid;
  const int r0 = s0 >> 2, c0 = (s0 & 3) ^ ((r0 >> 1) & 3);
  const int r1 = s1 >> 2, c1 = (s1 & 3) ^ ((r1 >> 1) & 3);
  const ushort* Ag0 = A + (size_t)(m0 + r0) * K + c0 * 8;
  const ushort* Ag1 = A + (size_t)(m0 + r1) * K + c1 * 8;
  const ushort* Bg0 = B + (size_t)(n0 + r0) * K + c0 * 8;
  const ushort* Bg1 = B + (size_t)(n0 + r1) * K + c1 * 8;

  for (int kt = 0; kt < K; kt += 32) {
    async16(Ag0 + kt, As + s0 * 8);
    async16(Ag1 + kt, As + s1 * 8);
    async16(Bg0 + kt, Bs + s0 * 8);
    async16(Bg1 + kt, Bs + s1 * 8);
    __syncthreads();
    bf16x8 af[4], bfr[4];
#pragma unroll
    for (int tm = 0; tm < 4; ++tm) {
      int r = wm + tm * 16 + l15;
      int cs = quad ^ ((r >> 1) & 3);
      af[tm] = *(const bf16x8*)(As + (r * 4 + cs) * 8);
    }
#pragma unroll
    for (int tn = 0; tn < 4; ++tn) {
      int r = wn + tn * 16 + l15;
      int cs = quad ^ ((r >> 1) & 3);
      bfr[tn] = *(const bf16x8*)(Bs + (r * 4 + cs) * 8);
    }
#pragma unroll
    for (int tm = 0; tm < 4; ++tm)
#pragma unroll
      for (int tn = 0; tn < 4; ++tn)
        acc[tm][tn] = __builtin_amdgcn_mfma_f32_16x16x32_bf16(af[tm], bfr[tn],
                                                              acc[tm][tn], 0, 0, 0);
    __syncthreads();
  }

  if (MODE == 0) {
#pragma unroll
    for (int tm = 0; tm < 4; ++tm)
#pragma unroll
      for (int tn = 0; tn < 4; ++tn) {
        int col = n0 + wn + tn * 16 + l15;
#pragma unroll
        for (int r = 0; r < 4; ++r) {
          int row = m0 + wm + tm * 16 + quad * 4 + r;
          outf[(size_t)row * 1024 + col] = acc[tm][tn][r];
        }
      }
  } else if (MODE == 1) {
    // col in [0,2048): head=col>>7, part=(col>>6)&1, d=col&63
#pragma unroll
    for (int tm = 0; tm < 4; ++tm)
#pragma unroll
      for (int tn = 0; tn < 4; ++tn) {
        int col = n0 + wn + tn * 16 + l15;
        int hd = col >> 7, part = (col >> 6) & 1, d = col & 63;
#pragma unroll
        for (int r = 0; r < 4; ++r) {
          int row = m0 + wm + tm * 16 + quad * 4 + r;
          int b = row >> 10, n = row & 1023;
          size_t bh = (size_t)b * 16 + hd;
          f16 v = (f16)acc[tm][tn][r];
          if (part == 0) qb[(bh * 1024 + n) * 64 + d] = v;
          else           kb[(bh * 1024 + n) * 64 + d] = v;
        }
      }
  } else {
    // V^T: row m = v-feature f (= hd*64+d), col = token (b*1024+nn)
#pragma unroll
    for (int tm = 0; tm < 4; ++tm)
#pragma unroll
      for (int tn = 0; tn < 4; ++tn) {
        int col = n0 + wn + tn * 16 + l15;
        int b = col >> 10, nn = col & 1023;
#pragma unroll
        for (int r = 0; r < 4; ++r) {
          int f = m0 + wm + tm * 16 + quad * 4 + r;
          vtb[((size_t)(b * 1024 + f)) * 1024 + nn] = (f16)acc[tm][tn][r];
        }
      }
  }
}

// ---------- kernel 5: 2D RoPE in-place (f16); q gets 0.125*log2(e) fold ----------
__global__ __launch_bounds__(256)
void rope_kernel(f16* __restrict__ qb, f16* __restrict__ kb) {
  size_t idx = (size_t)blockIdx.x * 256 + threadIdx.x;
  int p = (int)(idx & 31);
  size_t rowi = idx >> 5;
  int n = (int)(rowi & 1023);
  int j = p & 15;
  float pos = (p < 16) ? (float)(n & 31) : (float)(n >> 5);
  float theta = __powf(10000.f, -(float)j * (1.f / 16.f));
  float ang = pos * theta;
  float sn, cs;
  __sincosf(ang, &sn, &cs);
  const float QS = 0.125f * 1.44269504f;   // attn scale * log2(e), folded into q
  size_t a = rowi * 64 + (size_t)p * 2;
  union U { uint32_t u; f16 h[2]; };
  U qu; qu.u = *(const uint32_t*)(qb + a);
  float x0 = (float)qu.h[0], x1 = (float)qu.h[1];
  U qo;
  qo.h[0] = (f16)((x0 * cs - x1 * sn) * QS);
  qo.h[1] = (f16)((x1 * cs + x0 * sn) * QS);
  *(uint32_t*)(qb + a) = qo.u;
  U ku; ku.u = *(const uint32_t*)(kb + a);
  float k0 = (float)ku.h[0], k1 = (float)ku.h[1];
  U ko;
  ko.h[0] = (f16)(k0 * cs - k1 * sn);
  ko.h[1] = (f16)(k1 * cs + k0 * sn);
  *(uint32_t*)(kb + a) = ko.u;
}

// ---------- kernel 6: flash attention, in-register P (S^T trick), f16 MFMA ----------
// 1D grid 2048, swizzled: xcd = id%8 (round-robin XCD), consecutive id/8 walk
// all 8 q-blocks of one bh before advancing bh. Per-XCD resident working set
// ~12 bh x 256KB = 3MB <= 4MB L2.  launch_bounds(256,3): 170 regs/wave, no spill.
__global__ __launch_bounds__(256, 3)
void attn_kernel(const f16* __restrict__ qbuf, const f16* __restrict__ kbuf,
                 const f16* __restrict__ vtbuf, ushort* __restrict__ aout) {
  __shared__ f16 Ks[128 * 64];   // [krow][64d], 16B col c swizzled: c^(row&7)
  __shared__ f16 Vs[64 * 128];   // V^T [d][128k], 16B col c swizzled: c^(row&15)

  const int id = blockIdx.x;
  const int xcd = id & 7, j = id >> 3;
  const int bh = xcd * 32 + (j >> 3);
  const int q0 = (j & 7) * 128;
  const f16* Qg = qbuf + (size_t)bh * 1024 * 64;
  const f16* Kg = kbuf + (size_t)bh * 1024 * 64;
  const f16* Vg = vtbuf + (size_t)bh * 64 * 1024;
  const int tid = threadIdx.x;
  const int w = tid >> 6, lane = tid & 63, quad = lane >> 4, l15 = lane & 15;
  const f32x4 fzero = {0.f, 0.f, 0.f, 0.f};

  // Q B-fragments straight from global: B[n=q=l15][k=d=quad*4+i]
  f16x4 qf[2][4];
#pragma unroll
  for (int qs = 0; qs < 2; ++qs)
#pragma unroll
    for (int dc = 0; dc < 4; ++dc)
      qf[qs][dc] = *(const f16x4*)(Qg + (size_t)(q0 + w * 32 + qs * 16 + l15) * 64 +
                                   dc * 16 + quad * 4);

  f32x4 oacc[2][4];
#pragma unroll
  for (int qs = 0; qs < 2; ++qs)
#pragma unroll
    for (int ds = 0; ds < 4; ++ds) oacc[qs][ds] = fzero;
  float mrun[2] = {-1e30f, -1e30f}, lrun[2] = {0.f, 0.f};

  for (int kt = 0; kt < 1024; kt += 128) {
#pragma unroll
    for (int i = 0; i < 4; ++i) {       // K tile
      int u = i * 256 + tid, r = u >> 3, c = u & 7;
      async16(Kg + (size_t)(kt + r) * 64 + (c ^ (r & 7)) * 8, Ks + u * 8);
    }
#pragma unroll
    for (int i = 0; i < 4; ++i) {       // V^T tile
      int u = i * 256 + tid, r = u >> 4, c = u & 15;
      async16(Vg + (size_t)r * 1024 + kt + (c ^ (r & 15)) * 8, Vs + u * 8);
    }
    __syncthreads();

    // S^T: D[k=quad*4+r][q=l15], chained over d
    f32x4 sacc[2][8];
#pragma unroll
    for (int qs = 0; qs < 2; ++qs)
#pragma unroll
      for (int ks = 0; ks < 8; ++ks) sacc[qs][ks] = fzero;
#pragma unroll
    for (int ks = 0; ks < 8; ++ks) {
#pragma unroll
      for (int dc = 0; dc < 4; ++dc) {
        int row = ks * 16 + l15;
        int c16 = dc * 2 + (quad >> 1);
        f16x4 kf = *(const f16x4*)(Ks + row * 64 + ((c16 ^ (row & 7)) * 8) + (quad & 1) * 4);
        sacc[0][ks] = __builtin_amdgcn_mfma_f32_16x16x16f16(kf, qf[0][dc], sacc[0][ks], 0, 0, 0);
        sacc[1][ks] = __builtin_amdgcn_mfma_f32_16x16x16f16(kf, qf[1][dc], sacc[1][ks], 0, 0, 0);
      }
    }

    // online softmax fully in registers (lane owns q=l15; cross-quad shfl only)
    f16x4 pf[2][8];
#pragma unroll
    for (int qs = 0; qs < 2; ++qs) {
      float mx = -1e30f;
#pragma unroll
      for (int ks = 0; ks < 8; ++ks)
#pragma unroll
        for (int i = 0; i < 4; ++i) mx = fmaxf(mx, sacc[qs][ks][i]);
      mx = fmaxf(mx, __shfl_xor(mx, 16, 64));
      mx = fmaxf(mx, __shfl_xor(mx, 32, 64));
      float mnew = fmaxf(mrun[qs], mx);
      float alpha = exp2f(mrun[qs] - mnew);
      mrun[qs] = mnew;
      float rs = 0.f;
#pragma unroll
      for (int ks = 0; ks < 8; ++ks)
#pragma unroll
        for (int i = 0; i < 4; ++i) {
          float p = exp2f(sacc[qs][ks][i] - mnew);
          rs += p;
          pf[qs][ks][i] = (f16)p;
        }
      rs += __shfl_xor(rs, 16, 64);
      rs += __shfl_xor(rs, 32, 64);
      lrun[qs] = lrun[qs] * alpha + rs;
      float ar[4];
#pragma unroll
      for (int r = 0; r < 4; ++r) ar[r] = __shfl(alpha, quad * 4 + r, 64);
#pragma unroll
      for (int ds = 0; ds < 4; ++ds)
#pragma unroll
        for (int r = 0; r < 4; ++r) oacc[qs][ds][r] *= ar[r];
    }

    // O += P V : P already in A layout; V^T B-frag from LDS
#pragma unroll
    for (int ks = 0; ks < 8; ++ks) {
#pragma unroll
      for (int ds = 0; ds < 4; ++ds) {
        int row = ds * 16 + l15;
        int c16 = ks * 2 + (quad >> 1);
        f16x4 vf = *(const f16x4*)(Vs + row * 128 + ((c16 ^ (row & 15)) * 8) + (quad & 1) * 4);
        oacc[0][ds] = __builtin_amdgcn_mfma_f32_16x16x16f16(pf[0][ks], vf, oacc[0][ds], 0, 0, 0);
        oacc[1][ds] = __builtin_amdgcn_mfma_f32_16x16x16f16(pf[1][ks], vf, oacc[1][ds], 0, 0, 0);
      }
    }
    __syncthreads();
  }

  // epilogue: O /= l, write [b][n][h*64+d] bf16
  const int b = bh >> 4, hh = bh & 15;
#pragma unroll
  for (int qs = 0; qs < 2; ++qs) {
    float linv[4];
#pragma unroll
    for (int r = 0; r < 4; ++r) linv[r] = 1.f / __shfl(lrun[qs], quad * 4 + r, 64);
#pragma unroll
    for (int ds = 0; ds < 4; ++ds)
#pragma unroll
      for (int r = 0; r < 4; ++r) {
        int n = q0 + w * 32 + qs * 16 + quad * 4 + r;
        int d = ds * 16 + l15;
        aout[((size_t)b * 1024 + n) * 1024 + hh * 64 + d] = f2bf(oacc[qs][ds][r] * linv[r]);
      }
  }
}

// ---------- launch ----------
extern "C" void kernel_launch(void* const* d_in, const int* in_sizes, int n_in,
                              void* d_out, int out_size, void* d_ws, size_t ws_size,
                              hipStream_t stream) {
  const float* x    = (const float*)d_in[0];
  const float* t    = (const float*)d_in[1];
  const float* nw   = (const float*)d_in[2];
  const float* mw   = (const float*)d_in[3];
  const float* qkvw = (const float*)d_in[4];
  const float* wow  = (const float*)d_in[5];
  float* out = (float*)d_out;
  char* ws = (char*)d_ws;

  float*  modbuf  = (float*)(ws);                    // 131072 B
  ushort* hbuf    = (ushort*)(ws + 131072);          // 32 MB (bf16)
  ushort* wqk_b   = (ushort*)(ws + 33685504);        // 4 MB
  ushort* wv_b    = (ushort*)(ws + 37879808);        // 2 MB
  ushort* wow_b   = (ushort*)(ws + 39976960);        // 2 MB
  f16*    qbuf    = (f16*)(ws + 42074112);           // 32 MB
  f16*    kbuf    = (f16*)(ws + 75628544);           // 32 MB
  f16*    vtbuf   = (f16*)(ws + 109182976);          // 32 MB (V^T [b][f][n])
  ushort* abuf    = (ushort*)(ws + 142737408);       // 32 MB (bf16)

  mod_gemm_kernel<<<dim3(2048), dim3(64), 0, stream>>>(t, mw, modbuf);
  rms_mod_kernel<<<dim3(16384), dim3(256), 0, stream>>>(x, nw, modbuf, hbuf);
  cvt_split_kernel<<<dim3(3072), dim3(256), 0, stream>>>(qkvw, wqk_b, wv_b);
  cvt_bf16_kernel<<<dim3(1024), dim3(256), 0, stream>>>(wow, wow_b, 262144);
  gemm_bt_kernel<1><<<dim3(16, 128), dim3(256), 0, stream>>>(
      hbuf, wqk_b, nullptr, qbuf, kbuf, nullptr);
  gemm_bt_kernel<2><<<dim3(128, 8), dim3(256), 0, stream>>>(
      wv_b, hbuf, nullptr, nullptr, nullptr, vtbuf);
  rope_kernel<<<dim3(32768), dim3(256), 0, stream>>>(qbuf, kbuf);
  attn_kernel<<<dim3(2048), dim3(256), 0, stream>>>(qbuf, kbuf, vtbuf, abuf);
  gemm_bt_kernel<0><<<dim3(8, 128), dim3(256), 0, stream>>>(
      abuf, wow_b, out, nullptr, nullptr, nullptr);
}

// Round 5
// 485.824 us; speedup vs baseline: 1.4807x; 1.1083x over previous
//
#include <hip/hip_runtime.h>
#include <stdint.h>

// ---------- types ----------
typedef __bf16    bf16x8 __attribute__((ext_vector_type(8)));
typedef float     f32x4  __attribute__((ext_vector_type(4)));
typedef _Float16  f16;
typedef _Float16  f16x4  __attribute__((ext_vector_type(4)));
typedef _Float16  f16x8  __attribute__((ext_vector_type(8)));

#define DEV __device__ __forceinline__

DEV ushort f2bf(float f) {               // RTNE float -> bf16 bits
  union { float f; uint32_t u; } v; v.f = f;
  uint32_t u = v.u;
  return (ushort)((u + 0x7fffu + ((u >> 16) & 1u)) >> 16);
}

// async global->LDS, 16B per lane. LDS dest must be wave-uniform base + lane*16.
DEV void async16(const void* g, void* l) {
  __builtin_amdgcn_global_load_lds(
      (__attribute__((address_space(1))) void*)(uintptr_t)g,
      (__attribute__((address_space(3))) void*)(uint32_t)(uintptr_t)l,
      16, 0, 0);
}

// ---------- kernel 1: mod = t @ mod_w.T  (16 x 2048, K=1024, fp32) ----------
__global__ __launch_bounds__(64)
void mod_gemm_kernel(const float* __restrict__ t, const float* __restrict__ w,
                     float* __restrict__ mod) {
  int j = blockIdx.x;
  int lane = threadIdx.x;
  float wr[16];
#pragma unroll
  for (int i = 0; i < 16; ++i) wr[i] = w[(size_t)j * 1024 + lane + i * 64];
  for (int b = 0; b < 16; ++b) {
    float s = 0.f;
#pragma unroll
    for (int i = 0; i < 16; ++i) s += wr[i] * t[b * 1024 + lane + i * 64];
#pragma unroll
    for (int m = 32; m >= 1; m >>= 1) s += __shfl_xor(s, m, 64);
    if (lane == 0) mod[b * 2048 + j] = s;
  }
}

// ---------- kernel 2: RMSNorm + modulate -> bf16 h ----------
__global__ __launch_bounds__(256)
void rms_mod_kernel(const float* __restrict__ x, const float* __restrict__ nw,
                    const float* __restrict__ mod, ushort* __restrict__ h) {
  int row = blockIdx.x;
  int b = row >> 10;
  int tid = threadIdx.x;
  const float4 xv = *(const float4*)(x + (size_t)row * 1024 + tid * 4);
  float ss = xv.x * xv.x + xv.y * xv.y + xv.z * xv.z + xv.w * xv.w;
#pragma unroll
  for (int m = 32; m >= 1; m >>= 1) ss += __shfl_xor(ss, m, 64);
  __shared__ float red[4];
  int w = tid >> 6, lane = tid & 63;
  if (lane == 0) red[w] = ss;
  __syncthreads();
  float tot = red[0] + red[1] + red[2] + red[3];
  float rn = rsqrtf(tot * (1.f / 1024.f) + 1e-6f);
  float4 wv = *(const float4*)(nw + tid * 4);
  float4 sc = *(const float4*)(mod + (size_t)b * 2048 + tid * 4);
  float4 sh = *(const float4*)(mod + (size_t)b * 2048 + 1024 + tid * 4);
  ushort4 o;
  o.x = f2bf(xv.x * rn * wv.x * (1.f + sc.x) + sh.x);
  o.y = f2bf(xv.y * rn * wv.y * (1.f + sc.y) + sh.y);
  o.z = f2bf(xv.z * rn * wv.z * (1.f + sc.z) + sh.z);
  o.w = f2bf(xv.w * rn * wv.w * (1.f + sc.w) + sh.w);
  *(ushort4*)(h + (size_t)row * 1024 + tid * 4) = o;
}

// ---------- kernel 3: fp32 -> bf16 cast ----------
__global__ __launch_bounds__(256)
void cvt_bf16_kernel(const float* __restrict__ in, ushort* __restrict__ out, int n4) {
  int i = blockIdx.x * 256 + threadIdx.x;
  if (i < n4) {
    float4 v = ((const float4*)in)[i];
    ushort4 o;
    o.x = f2bf(v.x); o.y = f2bf(v.y); o.z = f2bf(v.z); o.w = f2bf(v.w);
    ((ushort4*)out)[i] = o;
  }
}

// ---------- kernel 3b: split qkv_w -> wqk (2048 rows) + wv (1024 rows), bf16
__global__ __launch_bounds__(256)
void cvt_split_kernel(const float* __restrict__ qkvw, ushort* __restrict__ wqk,
                      ushort* __restrict__ wv) {
  int j = blockIdx.x;                     // 0..3071
  int tid = threadIdx.x;
  uint32_t hd = (uint32_t)j / 192u;
  uint32_t rem = (uint32_t)j - hd * 192u;
  ushort* dst = (rem < 128u) ? (wqk + (size_t)(hd * 128u + rem) * 1024)
                             : (wv + (size_t)(hd * 64u + (rem - 128u)) * 1024);
  float4 v = ((const float4*)(qkvw + (size_t)j * 1024))[tid];
  ushort4 o;
  o.x = f2bf(v.x); o.y = f2bf(v.y); o.z = f2bf(v.z); o.w = f2bf(v.w);
  ((ushort4*)dst)[tid] = o;
}

// ---------- GEMM: C[M][N] = A[M][K] * B[N][K]^T, bf16 in, 128x128 tile ----------
// MODE 0: fp32 out (WO proj); A read from head-major abuf [b*16+hh][n][64]
// MODE 1: q/k f16 out, full-line stores via LDS transpose (N=2048)
// MODE 2: V^T f16 out [b][f][token], full-line stores via LDS transpose (N=16384)
template <int MODE>
__global__ __launch_bounds__(256, 3)
void gemm_bt_kernel(const ushort* __restrict__ A, const ushort* __restrict__ B,
                    float* __restrict__ outf,
                    f16* __restrict__ qb, f16* __restrict__ kb,
                    f16* __restrict__ vtb) {
  __shared__ ushort smem[8192];          // As (8KB) + Bs (8KB)
  ushort* As = smem;
  ushort* Bs = smem + 4096;
  const int K = 1024;
  const int m0 = blockIdx.y * 128, n0 = blockIdx.x * 128;
  const int tid = threadIdx.x;
  const int w = tid >> 6, lane = tid & 63, quad = lane >> 4, l15 = lane & 15;
  const int wm = (w >> 1) * 64, wn = (w & 1) * 64;
  const f32x4 fzero = {0.f, 0.f, 0.f, 0.f};
  f32x4 acc[4][4];
#pragma unroll
  for (int a = 0; a < 4; ++a)
#pragma unroll
    for (int b = 0; b < 4; ++b) acc[a][b] = fzero;

  const int s0 = tid, s1 = 256 + tid;
  const int r0 = s0 >> 2, c0 = (s0 & 3) ^ ((r0 >> 1) & 3);
  const int r1 = s1 >> 2, c1 = (s1 & 3) ^ ((r1 >> 1) & 3);
  const ushort *Ag0, *Ag1;
  if (MODE == 0) {
    // head-major abuf: elem(token m, k) at ((b*16 + (k>>6))*1024 + n)*64 + (k&63)
    const int b0 = m0 >> 10, nb = m0 & 1023;
    const size_t Abase = (size_t)b0 * 16 * 1024 * 64;
    Ag0 = A + Abase + (size_t)(nb + r0) * 64 + c0 * 8;
    Ag1 = A + Abase + (size_t)(nb + r1) * 64 + c1 * 8;
  } else {
    Ag0 = A + (size_t)(m0 + r0) * K + c0 * 8;
    Ag1 = A + (size_t)(m0 + r1) * K + c1 * 8;
  }
  const ushort* Bg0 = B + (size_t)(n0 + r0) * K + c0 * 8;
  const ushort* Bg1 = B + (size_t)(n0 + r1) * K + c1 * 8;

  for (int kt = 0; kt < K; kt += 32) {
    const size_t ka = (MODE == 0)
        ? ((size_t)(kt >> 6) * 65536 + (size_t)(kt & 63))
        : (size_t)kt;
    async16(Ag0 + ka, As + s0 * 8);
    async16(Ag1 + ka, As + s1 * 8);
    async16(Bg0 + kt, Bs + s0 * 8);
    async16(Bg1 + kt, Bs + s1 * 8);
    __syncthreads();
    bf16x8 af[4], bfr[4];
#pragma unroll
    for (int tm = 0; tm < 4; ++tm) {
      int r = wm + tm * 16 + l15;
      int cs = quad ^ ((r >> 1) & 3);
      af[tm] = *(const bf16x8*)(As + (r * 4 + cs) * 8);
    }
#pragma unroll
    for (int tn = 0; tn < 4; ++tn) {
      int r = wn + tn * 16 + l15;
      int cs = quad ^ ((r >> 1) & 3);
      bfr[tn] = *(const bf16x8*)(Bs + (r * 4 + cs) * 8);
    }
#pragma unroll
    for (int tm = 0; tm < 4; ++tm)
#pragma unroll
      for (int tn = 0; tn < 4; ++tn)
        acc[tm][tn] = __builtin_amdgcn_mfma_f32_16x16x32_bf16(af[tm], bfr[tn],
                                                              acc[tm][tn], 0, 0, 0);
    __syncthreads();
  }

  if (MODE == 0) {
#pragma unroll
    for (int tm = 0; tm < 4; ++tm)
#pragma unroll
      for (int tn = 0; tn < 4; ++tn) {
        int col = n0 + wn + tn * 16 + l15;
#pragma unroll
        for (int r = 0; r < 4; ++r) {
          int row = m0 + wm + tm * 16 + quad * 4 + r;
          outf[(size_t)row * 1024 + col] = acc[tm][tn][r];
        }
      }
  } else {
    // full-line stores via wave-private LDS transpose (64x64 quadrant, 2 groups)
    ushort* eps = smem + w * 2048;       // 4KB per wave
#pragma unroll
    for (int g = 0; g < 2; ++g) {
      __syncthreads();
#pragma unroll
      for (int ts = 0; ts < 2; ++ts) {
        int tm = g * 2 + ts;
#pragma unroll
        for (int tn = 0; tn < 4; ++tn)
#pragma unroll
          for (int r = 0; r < 4; ++r) {
            int row_loc = ts * 16 + quad * 4 + r;
            int col = tn * 16 + l15;
            int ch = (col >> 3) ^ (row_loc & 7);
            union { f16 h; ushort u; } cv;
            cv.h = (f16)acc[tm][tn][r];
            eps[row_loc * 64 + ch * 8 + (col & 7)] = cv.u;
          }
      }
      __syncthreads();
#pragma unroll
      for (int i = 0; i < 4; ++i) {
        int row_loc = i * 8 + (lane >> 3);
        int ch = lane & 7;
        uint4 v = *(const uint4*)(eps + row_loc * 64 + ((ch ^ (row_loc & 7)) * 8));
        int m = m0 + wm + g * 32 + row_loc;
        if (MODE == 1) {
          int hd = (n0 + wn) >> 7, part = ((n0 + wn) >> 6) & 1;
          int b = m >> 10, n = m & 1023;
          ushort* dst = (ushort*)(part ? kb : qb) +
                        (((size_t)(b * 16 + hd) * 1024 + n) * 64 + ch * 8);
          *(uint4*)dst = v;
        } else {
          int b = (n0 + wn) >> 10, nn = (n0 + wn) & 1023;
          ushort* dst = (ushort*)vtb +
                        ((size_t)(b * 1024 + m) * 1024 + nn + ch * 8);
          *(uint4*)dst = v;
        }
      }
    }
  }
}

// ---------- kernel 5: 2D RoPE in-place (f16); q gets 0.125*log2(e) fold ----------
__global__ __launch_bounds__(256)
void rope_kernel(f16* __restrict__ qb, f16* __restrict__ kb) {
  size_t idx = (size_t)blockIdx.x * 256 + threadIdx.x;
  int p = (int)(idx & 31);
  size_t rowi = idx >> 5;
  int n = (int)(rowi & 1023);
  int j = p & 15;
  float pos = (p < 16) ? (float)(n & 31) : (float)(n >> 5);
  float theta = __powf(10000.f, -(float)j * (1.f / 16.f));
  float ang = pos * theta;
  float sn, cs;
  __sincosf(ang, &sn, &cs);
  const float QS = 0.125f * 1.44269504f;   // attn scale * log2(e), folded into q
  size_t a = rowi * 64 + (size_t)p * 2;
  union U { uint32_t u; f16 h[2]; };
  U qu; qu.u = *(const uint32_t*)(qb + a);
  float x0 = (float)qu.h[0], x1 = (float)qu.h[1];
  U qo;
  qo.h[0] = (f16)((x0 * cs - x1 * sn) * QS);
  qo.h[1] = (f16)((x1 * cs + x0 * sn) * QS);
  *(uint32_t*)(qb + a) = qo.u;
  U ku; ku.u = *(const uint32_t*)(kb + a);
  float k0 = (float)ku.h[0], k1 = (float)ku.h[1];
  U ko;
  ko.h[0] = (f16)(k0 * cs - k1 * sn);
  ko.h[1] = (f16)(k1 * cs + k0 * sn);
  *(uint32_t*)(kb + a) = ko.u;
}

// ---------- kernel 6: flash attention, in-register P, x32 QK^T, x16 PV ----------
// 1D grid 2048, swizzled: xcd = id%8; consecutive id/8 walk q-blocks of one bh.
// Epilogue: wave-private LDS transpose -> 1KB-contiguous stores, head-major out.
__global__ __launch_bounds__(256, 3)
void attn_kernel(const f16* __restrict__ qbuf, const f16* __restrict__ kbuf,
                 const f16* __restrict__ vtbuf, ushort* __restrict__ aout) {
  __shared__ f16 Ks[128 * 64];   // [krow][64d], 16B chunk c swizzled: c^(row&7)
  __shared__ f16 Vs[64 * 128];   // V^T [d][128k], 16B chunk c swizzled: c^(row&15)

  const int id = blockIdx.x;
  const int xcd = id & 7, j = id >> 3;
  const int bh = xcd * 32 + (j >> 3);
  const int q0 = (j & 7) * 128;
  const f16* Qg = qbuf + (size_t)bh * 1024 * 64;
  const f16* Kg = kbuf + (size_t)bh * 1024 * 64;
  const f16* Vg = vtbuf + (size_t)bh * 64 * 1024;
  const int tid = threadIdx.x;
  const int w = tid >> 6, lane = tid & 63, quad = lane >> 4, l15 = lane & 15;
  const f32x4 fzero = {0.f, 0.f, 0.f, 0.f};

  // Q B-fragments (x32 layout): B[n=q=l15][k = dc*32 + quad*8 + i], b128 loads
  f16x8 qf[2][2];
#pragma unroll
  for (int qs = 0; qs < 2; ++qs)
#pragma unroll
    for (int dc = 0; dc < 2; ++dc)
      qf[qs][dc] = *(const f16x8*)(Qg + (size_t)(q0 + w * 32 + qs * 16 + l15) * 64 +
                                   dc * 32 + quad * 8);

  f32x4 oacc[2][4];
#pragma unroll
  for (int qs = 0; qs < 2; ++qs)
#pragma unroll
    for (int ds = 0; ds < 4; ++ds) oacc[qs][ds] = fzero;
  float mrun[2] = {-1e30f, -1e30f}, lrun[2] = {0.f, 0.f};

  for (int kt = 0; kt < 1024; kt += 128) {
#pragma unroll
    for (int i = 0; i < 4; ++i) {       // K tile
      int u = i * 256 + tid, r = u >> 3, c = u & 7;
      async16(Kg + (size_t)(kt + r) * 64 + (c ^ (r & 7)) * 8, Ks + u * 8);
    }
#pragma unroll
    for (int i = 0; i < 4; ++i) {       // V^T tile
      int u = i * 256 + tid, r = u >> 4, c = u & 15;
      async16(Vg + (size_t)r * 1024 + kt + (c ^ (r & 15)) * 8, Vs + u * 8);
    }
    __syncthreads();

    // S^T = K Q^T via 16x16x32: D[kv=quad*4+r][q=l15]
    f32x4 sacc[2][8];
#pragma unroll
    for (int qs = 0; qs < 2; ++qs)
#pragma unroll
      for (int ks = 0; ks < 8; ++ks) sacc[qs][ks] = fzero;
#pragma unroll
    for (int ks = 0; ks < 8; ++ks) {
#pragma unroll
      for (int dc = 0; dc < 2; ++dc) {
        int row = ks * 16 + l15;
        int ch = (dc * 4 + quad) ^ (row & 7);
        f16x8 kf = *(const f16x8*)(Ks + row * 64 + ch * 8);
        sacc[0][ks] = __builtin_amdgcn_mfma_f32_16x16x32_f16(kf, qf[0][dc], sacc[0][ks], 0, 0, 0);
        sacc[1][ks] = __builtin_amdgcn_mfma_f32_16x16x32_f16(kf, qf[1][dc], sacc[1][ks], 0, 0, 0);
      }
    }

    // online softmax fully in registers (lane owns q=l15; cross-quad shfl only)
    f16x4 pf[2][8];
#pragma unroll
    for (int qs = 0; qs < 2; ++qs) {
      float mx = -1e30f;
#pragma unroll
      for (int ks = 0; ks < 8; ++ks)
#pragma unroll
        for (int i = 0; i < 4; ++i) mx = fmaxf(mx, sacc[qs][ks][i]);
      mx = fmaxf(mx, __shfl_xor(mx, 16, 64));
      mx = fmaxf(mx, __shfl_xor(mx, 32, 64));
      float mnew = fmaxf(mrun[qs], mx);
      float alpha = exp2f(mrun[qs] - mnew);
      mrun[qs] = mnew;
      float rs = 0.f;
#pragma unroll
      for (int ks = 0; ks < 8; ++ks)
#pragma unroll
        for (int i = 0; i < 4; ++i) {
          float p = exp2f(sacc[qs][ks][i] - mnew);
          rs += p;
          pf[qs][ks][i] = (f16)p;
        }
      rs += __shfl_xor(rs, 16, 64);
      rs += __shfl_xor(rs, 32, 64);
      lrun[qs] = lrun[qs] * alpha + rs;
      float ar[4];
#pragma unroll
      for (int r = 0; r < 4; ++r) ar[r] = __shfl(alpha, quad * 4 + r, 64);
#pragma unroll
      for (int ds = 0; ds < 4; ++ds)
#pragma unroll
        for (int r = 0; r < 4; ++r) oacc[qs][ds][r] *= ar[r];
    }

    // O += P V : P already in x16 A layout; V^T B-frag from LDS
#pragma unroll
    for (int ks = 0; ks < 8; ++ks) {
#pragma unroll
      for (int ds = 0; ds < 4; ++ds) {
        int row = ds * 16 + l15;
        int c16 = ks * 2 + (quad >> 1);
        f16x4 vf = *(const f16x4*)(Vs + row * 128 + ((c16 ^ (row & 15)) * 8) + (quad & 1) * 4);
        oacc[0][ds] = __builtin_amdgcn_mfma_f32_16x16x16f16(pf[0][ks], vf, oacc[0][ds], 0, 0, 0);
        oacc[1][ds] = __builtin_amdgcn_mfma_f32_16x16x16f16(pf[1][ks], vf, oacc[1][ds], 0, 0, 0);
      }
    }
    __syncthreads();
  }

  // epilogue: O /= l -> bf16 via wave-private LDS transpose -> 1KB stores
  // head-major out: aout[(bh*1024 + n)*64 + d]
  ushort* eps = (ushort*)Ks + w * 2048;   // 4KB per wave
#pragma unroll
  for (int qs = 0; qs < 2; ++qs) {
    float linv[4];
#pragma unroll
    for (int r = 0; r < 4; ++r) linv[r] = 1.f / __shfl(lrun[qs], quad * 4 + r, 64);
#pragma unroll
    for (int ds = 0; ds < 4; ++ds)
#pragma unroll
      for (int r = 0; r < 4; ++r) {
        int row_loc = qs * 16 + quad * 4 + r;
        int col = ds * 16 + l15;
        int ch = (col >> 3) ^ (row_loc & 7);
        eps[row_loc * 64 + ch * 8 + (col & 7)] = f2bf(oacc[qs][ds][r] * linv[r]);
      }
  }
  __syncthreads();
  const size_t obase = ((size_t)bh * 1024 + q0 + w * 32) * 64;
#pragma unroll
  for (int i = 0; i < 4; ++i) {
    int row_loc = i * 8 + (lane >> 3);
    int ch = lane & 7;
    uint4 v = *(const uint4*)(eps + row_loc * 64 + ((ch ^ (row_loc & 7)) * 8));
    *(uint4*)(aout + obase + row_loc * 64 + ch * 8) = v;
  }
}

// ---------- launch ----------
extern "C" void kernel_launch(void* const* d_in, const int* in_sizes, int n_in,
                              void* d_out, int out_size, void* d_ws, size_t ws_size,
                              hipStream_t stream) {
  const float* x    = (const float*)d_in[0];
  const float* t    = (const float*)d_in[1];
  const float* nw   = (const float*)d_in[2];
  const float* mw   = (const float*)d_in[3];
  const float* qkvw = (const float*)d_in[4];
  const float* wow  = (const float*)d_in[5];
  float* out = (float*)d_out;
  char* ws = (char*)d_ws;

  float*  modbuf  = (float*)(ws);                    // 131072 B
  ushort* hbuf    = (ushort*)(ws + 131072);          // 32 MB (bf16)
  ushort* wqk_b   = (ushort*)(ws + 33685504);        // 4 MB
  ushort* wv_b    = (ushort*)(ws + 37879808);        // 2 MB
  ushort* wow_b   = (ushort*)(ws + 39976960);        // 2 MB
  f16*    qbuf    = (f16*)(ws + 42074112);           // 32 MB
  f16*    kbuf    = (f16*)(ws + 75628544);           // 32 MB
  f16*    vtbuf   = (f16*)(ws + 109182976);          // 32 MB (V^T [b][f][n])
  ushort* abuf    = (ushort*)(ws + 142737408);       // 32 MB (bf16, head-major)

  mod_gemm_kernel<<<dim3(2048), dim3(64), 0, stream>>>(t, mw, modbuf);
  rms_mod_kernel<<<dim3(16384), dim3(256), 0, stream>>>(x, nw, modbuf, hbuf);
  cvt_split_kernel<<<dim3(3072), dim3(256), 0, stream>>>(qkvw, wqk_b, wv_b);
  cvt_bf16_kernel<<<dim3(1024), dim3(256), 0, stream>>>(wow, wow_b, 262144);
  gemm_bt_kernel<1><<<dim3(16, 128), dim3(256), 0, stream>>>(
      hbuf, wqk_b, nullptr, qbuf, kbuf, nullptr);
  gemm_bt_kernel<2><<<dim3(128, 8), dim3(256), 0, stream>>>(
      wv_b, hbuf, nullptr, nullptr, nullptr, vtbuf);
  rope_kernel<<<dim3(32768), dim3(256), 0, stream>>>(qbuf, kbuf);
  attn_kernel<<<dim3(2048), dim3(256), 0, stream>>>(qbuf, kbuf, vtbuf, abuf);
  gemm_bt_kernel<0><<<dim3(8, 128), dim3(256), 0, stream>>>(
      abuf, wow_b, out, nullptr, nullptr, nullptr);
}

// Round 7
// 459.938 us; speedup vs baseline: 1.5640x; 1.0563x over previous
//
#include <hip/hip_runtime.h>
#include <stdint.h>

// ---------- types ----------
typedef __bf16    bf16x8 __attribute__((ext_vector_type(8)));
typedef float     f32x4  __attribute__((ext_vector_type(4)));
typedef _Float16  f16;
typedef _Float16  f16x2  __attribute__((ext_vector_type(2)));
typedef _Float16  f16x4  __attribute__((ext_vector_type(4)));
typedef _Float16  f16x8  __attribute__((ext_vector_type(8)));

#define DEV __device__ __forceinline__

DEV ushort f2bf(float f) {               // RTNE float -> bf16 bits
  union { float f; uint32_t u; } v; v.f = f;
  uint32_t u = v.u;
  return (ushort)((u + 0x7fffu + ((u >> 16) & 1u)) >> 16);
}

DEV f16x2 cvt_pkrtz(float a, float b) {  // v_cvt_pkrtz_f16_f32, bit-cast to f16x2
  return __builtin_bit_cast(f16x2, __builtin_amdgcn_cvt_pkrtz(a, b));
}

// async global->LDS, 16B per lane. LDS dest must be wave-uniform base + lane*16.
DEV void async16(const void* g, void* l) {
  __builtin_amdgcn_global_load_lds(
      (__attribute__((address_space(1))) void*)(uintptr_t)g,
      (__attribute__((address_space(3))) void*)(uint32_t)(uintptr_t)l,
      16, 0, 0);
}

// ---------- prep kernel: mod-gemm + weight split/cast + wo cast (one launch) ----
__global__ __launch_bounds__(256)
void prep_kernel(const float* __restrict__ t, const float* __restrict__ mw,
                 float* __restrict__ mod,
                 const float* __restrict__ qkvw, ushort* __restrict__ wqk,
                 ushort* __restrict__ wv,
                 const float* __restrict__ wow, ushort* __restrict__ wowb) {
  const int id = blockIdx.x;
  const int tid = threadIdx.x;
  if (id < 2048) {
    // mod = t @ mod_w.T : column j, wave w handles batches w*4..w*4+3
    const int j = id;
    const int w = tid >> 6, lane = tid & 63;
    float wr[16];
#pragma unroll
    for (int i = 0; i < 16; ++i) wr[i] = mw[(size_t)j * 1024 + lane + i * 64];
#pragma unroll
    for (int bb = 0; bb < 4; ++bb) {
      int b = w * 4 + bb;
      float s = 0.f;
#pragma unroll
      for (int i = 0; i < 16; ++i) s += wr[i] * t[b * 1024 + lane + i * 64];
#pragma unroll
      for (int m = 32; m >= 1; m >>= 1) s += __shfl_xor(s, m, 64);
      if (lane == 0) mod[b * 2048 + j] = s;
    }
  } else if (id < 5120) {
    // split qkv_w row j -> wqk (q,k interleaved per head) or wv
    const int j = id - 2048;
    uint32_t hd = (uint32_t)j / 192u;
    uint32_t rem = (uint32_t)j - hd * 192u;
    ushort* dst = (rem < 128u) ? (wqk + (size_t)(hd * 128u + rem) * 1024)
                               : (wv + (size_t)(hd * 64u + (rem - 128u)) * 1024);
    float4 v = ((const float4*)(qkvw + (size_t)j * 1024))[tid];
    ushort4 o;
    o.x = f2bf(v.x); o.y = f2bf(v.y); o.z = f2bf(v.z); o.w = f2bf(v.w);
    ((ushort4*)dst)[tid] = o;
  } else {
    // wo cast: 1024 blocks x 256 thr x float4
    const int i = (id - 5120) * 256 + tid;   // < 262144
    float4 v = ((const float4*)wow)[i];
    ushort4 o;
    o.x = f2bf(v.x); o.y = f2bf(v.y); o.z = f2bf(v.z); o.w = f2bf(v.w);
    ((ushort4*)wowb)[i] = o;
  }
}

// ---------- RMSNorm + modulate -> bf16 h ----------
__global__ __launch_bounds__(256)
void rms_mod_kernel(const float* __restrict__ x, const float* __restrict__ nw,
                    const float* __restrict__ mod, ushort* __restrict__ h) {
  int row = blockIdx.x;
  int b = row >> 10;
  int tid = threadIdx.x;
  const float4 xv = *(const float4*)(x + (size_t)row * 1024 + tid * 4);
  float ss = xv.x * xv.x + xv.y * xv.y + xv.z * xv.z + xv.w * xv.w;
#pragma unroll
  for (int m = 32; m >= 1; m >>= 1) ss += __shfl_xor(ss, m, 64);
  __shared__ float red[4];
  int w = tid >> 6, lane = tid & 63;
  if (lane == 0) red[w] = ss;
  __syncthreads();
  float tot = red[0] + red[1] + red[2] + red[3];
  float rn = rsqrtf(tot * (1.f / 1024.f) + 1e-6f);
  float4 wv = *(const float4*)(nw + tid * 4);
  float4 sc = *(const float4*)(mod + (size_t)b * 2048 + tid * 4);
  float4 sh = *(const float4*)(mod + (size_t)b * 2048 + 1024 + tid * 4);
  ushort4 o;
  o.x = f2bf(xv.x * rn * wv.x * (1.f + sc.x) + sh.x);
  o.y = f2bf(xv.y * rn * wv.y * (1.f + sc.y) + sh.y);
  o.z = f2bf(xv.z * rn * wv.z * (1.f + sc.z) + sh.z);
  o.w = f2bf(xv.w * rn * wv.w * (1.f + sc.w) + sh.w);
  *(ushort4*)(h + (size_t)row * 1024 + tid * 4) = o;
}

// ---------- QKV GEMM (merged): mode1 = q/k proj + fused RoPE, mode2 = V^T ------
// C[M][N] = A[M][K] * B[N][K]^T, bf16 in, 128x128 tile, full-line f16 stores.
__global__ __launch_bounds__(256, 3)
void gemm_qkv_kernel(const ushort* __restrict__ hbuf, const ushort* __restrict__ wqk,
                     const ushort* __restrict__ wvw,
                     f16* __restrict__ qb, f16* __restrict__ kb,
                     f16* __restrict__ vtb) {
  __shared__ ushort smem[8192];          // As (8KB) + Bs (8KB)
  ushort* As = smem;
  ushort* Bs = smem + 4096;
  const int K = 1024;
  const int id = blockIdx.x;
  int mode, m0, n0;
  const ushort *A, *B;
  if (id < 2048) {                       // q/k: cols 0..2047, rows 0..16383
    mode = 1; n0 = (id & 15) * 128; m0 = (id >> 4) * 128; A = hbuf; B = wqk;
  } else {                               // V^T: rows = v-features, cols = tokens
    int i2 = id - 2048;
    mode = 2; n0 = (i2 >> 3) * 128; m0 = (i2 & 7) * 128; A = wvw; B = hbuf;
  }
  const int tid = threadIdx.x;
  const int w = tid >> 6, lane = tid & 63, quad = lane >> 4, l15 = lane & 15;
  const int wm = (w >> 1) * 64, wn = (w & 1) * 64;
  const f32x4 fzero = {0.f, 0.f, 0.f, 0.f};
  f32x4 acc[4][4];
#pragma unroll
  for (int a = 0; a < 4; ++a)
#pragma unroll
    for (int b = 0; b < 4; ++b) acc[a][b] = fzero;

  const int s0 = tid, s1 = 256 + tid;
  const int r0 = s0 >> 2, c0 = (s0 & 3) ^ ((r0 >> 1) & 3);
  const int r1 = s1 >> 2, c1 = (s1 & 3) ^ ((r1 >> 1) & 3);
  const ushort* Ag0 = A + (size_t)(m0 + r0) * K + c0 * 8;
  const ushort* Ag1 = A + (size_t)(m0 + r1) * K + c1 * 8;
  const ushort* Bg0 = B + (size_t)(n0 + r0) * K + c0 * 8;
  const ushort* Bg1 = B + (size_t)(n0 + r1) * K + c1 * 8;

  for (int kt = 0; kt < K; kt += 32) {
    async16(Ag0 + kt, As + s0 * 8);
    async16(Ag1 + kt, As + s1 * 8);
    async16(Bg0 + kt, Bs + s0 * 8);
    async16(Bg1 + kt, Bs + s1 * 8);
    __syncthreads();
    bf16x8 af[4], bfr[4];
#pragma unroll
    for (int tm = 0; tm < 4; ++tm) {
      int r = wm + tm * 16 + l15;
      int cs = quad ^ ((r >> 1) & 3);
      af[tm] = *(const bf16x8*)(As + (r * 4 + cs) * 8);
    }
#pragma unroll
    for (int tn = 0; tn < 4; ++tn) {
      int r = wn + tn * 16 + l15;
      int cs = quad ^ ((r >> 1) & 3);
      bfr[tn] = *(const bf16x8*)(Bs + (r * 4 + cs) * 8);
    }
#pragma unroll
    for (int tm = 0; tm < 4; ++tm)
#pragma unroll
      for (int tn = 0; tn < 4; ++tn)
        acc[tm][tn] = __builtin_amdgcn_mfma_f32_16x16x32_bf16(af[tm], bfr[tn],
                                                              acc[tm][tn], 0, 0, 0);
    __syncthreads();
  }

  // epilogue: wave-private LDS transpose (64x64 quadrant, 2 groups) -> full lines
  ushort* eps = smem + w * 2048;         // 4KB per wave
  const int hd = (n0 + wn) >> 7, part = ((n0 + wn) >> 6) & 1;   // mode1 only
  const float QS = part ? 1.f : 0.125f * 1.44269504f;  // q: scale*log2e fold
#pragma unroll
  for (int g = 0; g < 2; ++g) {
    __syncthreads();
#pragma unroll
    for (int ts = 0; ts < 2; ++ts) {
      int tm = g * 2 + ts;
#pragma unroll
      for (int tn = 0; tn < 4; ++tn)
#pragma unroll
        for (int r = 0; r < 4; ++r) {
          int row_loc = ts * 16 + quad * 4 + r;
          int col = tn * 16 + l15;
          int ch = (col >> 3) ^ (row_loc & 7);
          union { f16 h; ushort u; } cv;
          cv.h = (f16)acc[tm][tn][r];
          eps[row_loc * 64 + ch * 8 + (col & 7)] = cv.u;
        }
    }
    __syncthreads();
#pragma unroll
    for (int i = 0; i < 4; ++i) {
      int row_loc = i * 8 + (lane >> 3);
      int ch = lane & 7;
      union { uint4 u4; f16 h[8]; } uv;
      uv.u4 = *(const uint4*)(eps + row_loc * 64 + ((ch ^ (row_loc & 7)) * 8));
      int m = m0 + wm + g * 32 + row_loc;
      if (mode == 1) {
        // fused 2D RoPE on 4 pairs (d = ch*8 .. ch*8+7), f32 math
        int n = m & 1023;
#pragma unroll
        for (int t2 = 0; t2 < 4; ++t2) {
          int p = ch * 4 + t2;
          int jj = p & 15;
          float pos = (p < 16) ? (float)(n & 31) : (float)(n >> 5);
          float theta = __expf(-(float)jj * 0.5756462732485114f);  // ln(1e4)/16
          float sn, cs;
          __sincosf(pos * theta, &sn, &cs);
          float x0 = (float)uv.h[2 * t2], x1 = (float)uv.h[2 * t2 + 1];
          f16x2 ro = cvt_pkrtz((x0 * cs - x1 * sn) * QS,
                               (x1 * cs + x0 * sn) * QS);
          uv.h[2 * t2] = ro[0];
          uv.h[2 * t2 + 1] = ro[1];
        }
        int b = m >> 10;
        ushort* dst = (ushort*)(part ? kb : qb) +
                      (((size_t)(b * 16 + hd) * 1024 + n) * 64 + ch * 8);
        *(uint4*)dst = uv.u4;
      } else {
        int b = (n0 + wn) >> 10, nn = (n0 + wn) & 1023;
        ushort* dst = (ushort*)vtb +
                      ((size_t)(b * 1024 + m) * 1024 + nn + ch * 8);
        *(uint4*)dst = uv.u4;
      }
    }
  }
}

// ---------- WO GEMM: out[16384][1024] fp32 = abuf(head-major) @ wow^T ----------
__global__ __launch_bounds__(256, 3)
void gemm_wo_kernel(const ushort* __restrict__ A, const ushort* __restrict__ B,
                    float* __restrict__ outf) {
  __shared__ ushort smem[8192];
  ushort* As = smem;
  ushort* Bs = smem + 4096;
  const int K = 1024;
  const int m0 = blockIdx.y * 128, n0 = blockIdx.x * 128;
  const int tid = threadIdx.x;
  const int w = tid >> 6, lane = tid & 63, quad = lane >> 4, l15 = lane & 15;
  const int wm = (w >> 1) * 64, wn = (w & 1) * 64;
  const f32x4 fzero = {0.f, 0.f, 0.f, 0.f};
  f32x4 acc[4][4];
#pragma unroll
  for (int a = 0; a < 4; ++a)
#pragma unroll
    for (int b = 0; b < 4; ++b) acc[a][b] = fzero;

  const int s0 = tid, s1 = 256 + tid;
  const int r0 = s0 >> 2, c0 = (s0 & 3) ^ ((r0 >> 1) & 3);
  const int r1 = s1 >> 2, c1 = (s1 & 3) ^ ((r1 >> 1) & 3);
  // head-major abuf: elem(token m, k) at ((b*16 + (k>>6))*1024 + n)*64 + (k&63)
  const int b0 = m0 >> 10, nb = m0 & 1023;
  const size_t Abase = (size_t)b0 * 16 * 1024 * 64;
  const ushort* Ag0 = A + Abase + (size_t)(nb + r0) * 64 + c0 * 8;
  const ushort* Ag1 = A + Abase + (size_t)(nb + r1) * 64 + c1 * 8;
  const ushort* Bg0 = B + (size_t)(n0 + r0) * K + c0 * 8;
  const ushort* Bg1 = B + (size_t)(n0 + r1) * K + c1 * 8;

  for (int kt = 0; kt < K; kt += 32) {
    const size_t ka = (size_t)(kt >> 6) * 65536 + (size_t)(kt & 63);
    async16(Ag0 + ka, As + s0 * 8);
    async16(Ag1 + ka, As + s1 * 8);
    async16(Bg0 + kt, Bs + s0 * 8);
    async16(Bg1 + kt, Bs + s1 * 8);
    __syncthreads();
    bf16x8 af[4], bfr[4];
#pragma unroll
    for (int tm = 0; tm < 4; ++tm) {
      int r = wm + tm * 16 + l15;
      int cs = quad ^ ((r >> 1) & 3);
      af[tm] = *(const bf16x8*)(As + (r * 4 + cs) * 8);
    }
#pragma unroll
    for (int tn = 0; tn < 4; ++tn) {
      int r = wn + tn * 16 + l15;
      int cs = quad ^ ((r >> 1) & 3);
      bfr[tn] = *(const bf16x8*)(Bs + (r * 4 + cs) * 8);
    }
#pragma unroll
    for (int tm = 0; tm < 4; ++tm)
#pragma unroll
      for (int tn = 0; tn < 4; ++tn)
        acc[tm][tn] = __builtin_amdgcn_mfma_f32_16x16x32_bf16(af[tm], bfr[tn],
                                                              acc[tm][tn], 0, 0, 0);
    __syncthreads();
  }

#pragma unroll
  for (int tm = 0; tm < 4; ++tm)
#pragma unroll
    for (int tn = 0; tn < 4; ++tn) {
      int col = n0 + wn + tn * 16 + l15;
#pragma unroll
      for (int r = 0; r < 4; ++r) {
        int row = m0 + wm + tm * 16 + quad * 4 + r;
        outf[(size_t)row * 1024 + col] = acc[tm][tn][r];
      }
    }
}

// ---------- flash attention, in-register P, x32 QK^T, x16 PV ----------
// 1D grid 2048, swizzled: xcd = id%8; consecutive id/8 walk q-blocks of one bh.
__global__ __launch_bounds__(256, 3)
void attn_kernel(const f16* __restrict__ qbuf, const f16* __restrict__ kbuf,
                 const f16* __restrict__ vtbuf, ushort* __restrict__ aout) {
  __shared__ f16 Ks[128 * 64];   // [krow][64d], 16B chunk c swizzled: c^(row&7)
  __shared__ f16 Vs[64 * 128];   // V^T [d][128k], 16B chunk c swizzled: c^(row&15)

  const int id = blockIdx.x;
  const int xcd = id & 7, j = id >> 3;
  const int bh = xcd * 32 + (j >> 3);
  const int q0 = (j & 7) * 128;
  const f16* Qg = qbuf + (size_t)bh * 1024 * 64;
  const f16* Kg = kbuf + (size_t)bh * 1024 * 64;
  const f16* Vg = vtbuf + (size_t)bh * 64 * 1024;
  const int tid = threadIdx.x;
  const int w = tid >> 6, lane = tid & 63, quad = lane >> 4, l15 = lane & 15;
  const f32x4 fzero = {0.f, 0.f, 0.f, 0.f};

  // Q B-fragments (x32 layout): B[n=q=l15][k = dc*32 + quad*8 + i], b128 loads
  f16x8 qf[2][2];
#pragma unroll
  for (int qs = 0; qs < 2; ++qs)
#pragma unroll
    for (int dc = 0; dc < 2; ++dc)
      qf[qs][dc] = *(const f16x8*)(Qg + (size_t)(q0 + w * 32 + qs * 16 + l15) * 64 +
                                   dc * 32 + quad * 8);

  f32x4 oacc[2][4];
#pragma unroll
  for (int qs = 0; qs < 2; ++qs)
#pragma unroll
    for (int ds = 0; ds < 4; ++ds) oacc[qs][ds] = fzero;
  float mrun[2] = {-1e30f, -1e30f}, lrun[2] = {0.f, 0.f};

  for (int kt = 0; kt < 1024; kt += 128) {
#pragma unroll
    for (int i = 0; i < 4; ++i) {       // K tile
      int u = i * 256 + tid, r = u >> 3, c = u & 7;
      async16(Kg + (size_t)(kt + r) * 64 + (c ^ (r & 7)) * 8, Ks + u * 8);
    }
#pragma unroll
    for (int i = 0; i < 4; ++i) {       // V^T tile
      int u = i * 256 + tid, r = u >> 4, c = u & 15;
      async16(Vg + (size_t)r * 1024 + kt + (c ^ (r & 15)) * 8, Vs + u * 8);
    }
    __syncthreads();

    // S^T = K Q^T via 16x16x32: D[kv=quad*4+r][q=l15]
    f32x4 sacc[2][8];
#pragma unroll
    for (int qs = 0; qs < 2; ++qs)
#pragma unroll
      for (int ks = 0; ks < 8; ++ks) sacc[qs][ks] = fzero;
#pragma unroll
    for (int ks = 0; ks < 8; ++ks) {
#pragma unroll
      for (int dc = 0; dc < 2; ++dc) {
        int row = ks * 16 + l15;
        int ch = (dc * 4 + quad) ^ (row & 7);
        f16x8 kf = *(const f16x8*)(Ks + row * 64 + ch * 8);
        sacc[0][ks] = __builtin_amdgcn_mfma_f32_16x16x32_f16(kf, qf[0][dc], sacc[0][ks], 0, 0, 0);
        sacc[1][ks] = __builtin_amdgcn_mfma_f32_16x16x32_f16(kf, qf[1][dc], sacc[1][ks], 0, 0, 0);
      }
    }

    // online softmax fully in registers (lane owns q=l15; cross-quad shfl only)
    f16x4 pf[2][8];
#pragma unroll
    for (int qs = 0; qs < 2; ++qs) {
      const float* sv = (const float*)&sacc[qs][0];
      float mx = fmaxf(sv[0], sv[1]);
#pragma unroll
      for (int k = 2; k < 32; k += 2)      // v_max3 pairs
        mx = fmaxf(fmaxf(mx, sv[k]), sv[k + 1]);
      mx = fmaxf(mx, __shfl_xor(mx, 16, 64));
      mx = fmaxf(mx, __shfl_xor(mx, 32, 64));
      float mnew = fmaxf(mrun[qs], mx);
      float alpha = exp2f(mrun[qs] - mnew);
      mrun[qs] = mnew;
      float rs = 0.f;
#pragma unroll
      for (int ks = 0; ks < 8; ++ks) {
        float p0 = exp2f(sacc[qs][ks][0] - mnew);
        float p1 = exp2f(sacc[qs][ks][1] - mnew);
        float p2 = exp2f(sacc[qs][ks][2] - mnew);
        float p3 = exp2f(sacc[qs][ks][3] - mnew);
        rs += (p0 + p1) + (p2 + p3);
        union { f16x4 v; f16x2 h[2]; } pu;
        pu.h[0] = cvt_pkrtz(p0, p1);
        pu.h[1] = cvt_pkrtz(p2, p3);
        pf[qs][ks] = pu.v;
      }
      rs += __shfl_xor(rs, 16, 64);
      rs += __shfl_xor(rs, 32, 64);
      lrun[qs] = lrun[qs] * alpha + rs;
      float ar[4];
#pragma unroll
      for (int r = 0; r < 4; ++r) ar[r] = __shfl(alpha, quad * 4 + r, 64);
#pragma unroll
      for (int ds = 0; ds < 4; ++ds)
#pragma unroll
        for (int r = 0; r < 4; ++r) oacc[qs][ds][r] *= ar[r];
    }

    // O += P V : P already in x16 A layout; V^T B-frag from LDS
#pragma unroll
    for (int ks = 0; ks < 8; ++ks) {
#pragma unroll
      for (int ds = 0; ds < 4; ++ds) {
        int row = ds * 16 + l15;
        int c16 = ks * 2 + (quad >> 1);
        f16x4 vf = *(const f16x4*)(Vs + row * 128 + ((c16 ^ (row & 15)) * 8) + (quad & 1) * 4);
        oacc[0][ds] = __builtin_amdgcn_mfma_f32_16x16x16f16(pf[0][ks], vf, oacc[0][ds], 0, 0, 0);
        oacc[1][ds] = __builtin_amdgcn_mfma_f32_16x16x16f16(pf[1][ks], vf, oacc[1][ds], 0, 0, 0);
      }
    }
    __syncthreads();
  }

  // epilogue: O /= l -> bf16 via wave-private LDS transpose -> 1KB stores
  // head-major out: aout[(bh*1024 + n)*64 + d]
  ushort* eps = (ushort*)Ks + w * 2048;   // 4KB per wave
#pragma unroll
  for (int qs = 0; qs < 2; ++qs) {
    float linv[4];
#pragma unroll
    for (int r = 0; r < 4; ++r) linv[r] = 1.f / __shfl(lrun[qs], quad * 4 + r, 64);
#pragma unroll
    for (int ds = 0; ds < 4; ++ds)
#pragma unroll
      for (int r = 0; r < 4; ++r) {
        int row_loc = qs * 16 + quad * 4 + r;
        int col = ds * 16 + l15;
        int ch = (col >> 3) ^ (row_loc & 7);
        eps[row_loc * 64 + ch * 8 + (col & 7)] = f2bf(oacc[qs][ds][r] * linv[r]);
      }
  }
  __syncthreads();
  const size_t obase = ((size_t)bh * 1024 + q0 + w * 32) * 64;
#pragma unroll
  for (int i = 0; i < 4; ++i) {
    int row_loc = i * 8 + (lane >> 3);
    int ch = lane & 7;
    uint4 v = *(const uint4*)(eps + row_loc * 64 + ((ch ^ (row_loc & 7)) * 8));
    *(uint4*)(aout + obase + row_loc * 64 + ch * 8) = v;
  }
}

// ---------- launch ----------
extern "C" void kernel_launch(void* const* d_in, const int* in_sizes, int n_in,
                              void* d_out, int out_size, void* d_ws, size_t ws_size,
                              hipStream_t stream) {
  const float* x    = (const float*)d_in[0];
  const float* t    = (const float*)d_in[1];
  const float* nw   = (const float*)d_in[2];
  const float* mw   = (const float*)d_in[3];
  const float* qkvw = (const float*)d_in[4];
  const float* wow  = (const float*)d_in[5];
  float* out = (float*)d_out;
  char* ws = (char*)d_ws;

  float*  modbuf  = (float*)(ws);                    // 131072 B
  ushort* hbuf    = (ushort*)(ws + 131072);          // 32 MB (bf16)
  ushort* wqk_b   = (ushort*)(ws + 33685504);        // 4 MB
  ushort* wv_b    = (ushort*)(ws + 37879808);        // 2 MB
  ushort* wow_b   = (ushort*)(ws + 39976960);        // 2 MB
  f16*    qbuf    = (f16*)(ws + 42074112);           // 32 MB (rope+scale applied)
  f16*    kbuf    = (f16*)(ws + 75628544);           // 32 MB (rope applied)
  f16*    vtbuf   = (f16*)(ws + 109182976);          // 32 MB (V^T [b][f][n])
  ushort* abuf    = (ushort*)(ws + 142737408);       // 32 MB (bf16, head-major)

  prep_kernel<<<dim3(6144), dim3(256), 0, stream>>>(
      t, mw, modbuf, qkvw, wqk_b, wv_b, wow, wow_b);
  rms_mod_kernel<<<dim3(16384), dim3(256), 0, stream>>>(x, nw, modbuf, hbuf);
  gemm_qkv_kernel<<<dim3(3072), dim3(256), 0, stream>>>(
      hbuf, wqk_b, wv_b, qbuf, kbuf, vtbuf);
  attn_kernel<<<dim3(2048), dim3(256), 0, stream>>>(qbuf, kbuf, vtbuf, abuf);
  gemm_wo_kernel<<<dim3(8, 128), dim3(256), 0, stream>>>(abuf, wow_b, out);
}